// Round 1
// baseline (178.389 us; speedup 1.0000x reference)
//
#include <hip/hip_runtime.h>

typedef unsigned int u32;

#define BSZ 8
#define PN  2048
#define CIN 512

// ---------------- K1: xr = inputs @ fc_w + fc_b ; logit = softmax(xr) --------
// wave-per-row: lane l covers k = 4l..4l+3 and 256+4l..256+4l+3 (coalesced
// float4 loads, 1 KB per wave instruction), shuffle-reduce 4 accumulators.
__global__ __launch_bounds__(256) void k_fc_softmax(
    const float* __restrict__ inp, const float* __restrict__ fcw,
    const float* __restrict__ fcb, float* __restrict__ logit)
{
  const int gw   = (blockIdx.x * blockDim.x + threadIdx.x) >> 6; // 0..4095
  const int lane = threadIdx.x & 63;
  const int kb   = lane << 2;

  const float4 wa0 = *(const float4*)(fcw + (kb + 0) * 4);
  const float4 wa1 = *(const float4*)(fcw + (kb + 1) * 4);
  const float4 wa2 = *(const float4*)(fcw + (kb + 2) * 4);
  const float4 wa3 = *(const float4*)(fcw + (kb + 3) * 4);
  const float4 wb0 = *(const float4*)(fcw + (256 + kb + 0) * 4);
  const float4 wb1 = *(const float4*)(fcw + (256 + kb + 1) * 4);
  const float4 wb2 = *(const float4*)(fcw + (256 + kb + 2) * 4);
  const float4 wb3 = *(const float4*)(fcw + (256 + kb + 3) * 4);
  const float4 bias = *(const float4*)fcb;

  #pragma unroll
  for (int rr = 0; rr < 4; ++rr) {
    const int r = (gw << 2) + rr;                 // row 0..16383
    const float* row = inp + r * CIN;
    const float4 xa = *(const float4*)(row + kb);
    const float4 xb = *(const float4*)(row + 256 + kb);
    float a0 = xa.x*wa0.x + xa.y*wa1.x + xa.z*wa2.x + xa.w*wa3.x
             + xb.x*wb0.x + xb.y*wb1.x + xb.z*wb2.x + xb.w*wb3.x;
    float a1 = xa.x*wa0.y + xa.y*wa1.y + xa.z*wa2.y + xa.w*wa3.y
             + xb.x*wb0.y + xb.y*wb1.y + xb.z*wb2.y + xb.w*wb3.y;
    float a2 = xa.x*wa0.z + xa.y*wa1.z + xa.z*wa2.z + xa.w*wa3.z
             + xb.x*wb0.z + xb.y*wb1.z + xb.z*wb2.z + xb.w*wb3.z;
    float a3 = xa.x*wa0.w + xa.y*wa1.w + xa.z*wa2.w + xa.w*wa3.w
             + xb.x*wb0.w + xb.y*wb1.w + xb.z*wb2.w + xb.w*wb3.w;
    #pragma unroll
    for (int off = 32; off; off >>= 1) {
      a0 += __shfl_xor(a0, off);
      a1 += __shfl_xor(a1, off);
      a2 += __shfl_xor(a2, off);
      a3 += __shfl_xor(a3, off);
    }
    if (lane == 0) {
      a0 += bias.x; a1 += bias.y; a2 += bias.z; a3 += bias.w;
      const float m  = fmaxf(fmaxf(a0, a1), fmaxf(a2, a3));
      const float e0 = expf(a0 - m), e1 = expf(a1 - m);
      const float e2 = expf(a2 - m), e3 = expf(a3 - m);
      const float inv = 1.0f / (e0 + e1 + e2 + e3);
      float4 o; o.x = e0 * inv; o.y = e1 * inv; o.z = e2 * inv; o.w = e3 * inv;
      *(float4*)(logit + r * 4) = o;
    }
  }
}

// ---------------- K2: per-(b,c) selection mask -------------------------------
// sel_j = (labels[b,c]!=0) && (cnt>1 ? s_j>0.5 : j==argmax(s))
__global__ __launch_bounds__(256) void k_select(
    const float* __restrict__ ps, const float* __restrict__ labels,
    unsigned char* __restrict__ sel)
{
  const int b = blockIdx.x / 3;
  const int c = blockIdx.x % 3;
  const int t = threadIdx.x;

  float sv[8];
  int   cnt  = 0;
  float vmax = -1e30f;
  int   jmax = 0;
  #pragma unroll
  for (int m = 0; m < 8; ++m) {
    const int j = t + (m << 8);
    const float s = ps[(b * PN + j) * 4 + c];
    sv[m] = s;
    cnt += (s > 0.5f) ? 1 : 0;
    if (s > vmax) { vmax = s; jmax = j; }   // ascending j: strict > keeps first
  }

  __shared__ float lv[256];
  __shared__ int   lj[256];
  __shared__ int   lc[256];
  lv[t] = vmax; lj[t] = jmax; lc[t] = cnt;
  __syncthreads();
  for (int off = 128; off > 0; off >>= 1) {
    if (t < off) {
      lc[t] += lc[t + off];
      const float v2 = lv[t + off];
      const int   j2 = lj[t + off];
      if (v2 > lv[t] || (v2 == lv[t] && j2 < lj[t])) { lv[t] = v2; lj[t] = j2; }
    }
    __syncthreads();
  }
  const int  cntAll = lc[0];
  const int  jArg   = lj[0];
  const bool lab    = labels[b * 4 + c] != 0.0f;
  unsigned char* dst = sel + (b * 3 + c) * PN;
  #pragma unroll
  for (int m = 0; m < 8; ++m) {
    const int j = t + (m << 8);
    const bool se = (cntAll > 1) ? (sv[m] > 0.5f) : (j == jArg);
    dst[j] = (lab && se) ? 1 : 0;
  }
}

// ---------------- K3: IoU argmax + labels/weights + loss partials ------------
// block = (b, tile of 64 i). lanes = i, waves = j-chunks of 512.
// All lanes of a wave read the SAME j -> LDS broadcast (free).
// best tracked as rational (inter, union): divide once at the end; monotone
// rounding makes the max VALUE bit-identical to the reference.
__global__ __launch_bounds__(256) void k_assign(
    const float* __restrict__ rois, const float* __restrict__ ps,
    const float* __restrict__ labels, const unsigned char* __restrict__ sel,
    const float* __restrict__ logit, float* __restrict__ accum)
{
  const int b     = blockIdx.x >> 5;
  const int itile = blockIdx.x & 31;
  const int t     = threadIdx.x;

  __shared__ float4 sroi[PN];          // 32 KB
  __shared__ u32    ssel32[PN / 4];    // 2 KB (3 sel bits per j, byte-packed)
  __shared__ float  rnLDS[4][64][3];
  __shared__ float  rdLDS[4][64][3];
  __shared__ int    rjLDS[4][64][3];

  { // staging
    const float4* rb = ((const float4*)rois) + b * PN;
    #pragma unroll
    for (int m = 0; m < 8; ++m) {
      const int j = t + (m << 8);
      sroi[j] = rb[j];                 // coalesced 16B/lane
    }
    const int j8 = t * 8;
    const unsigned char* s0 = sel + (b * 3) * PN;
    const uint2 a0 = *(const uint2*)(s0 + j8);
    const uint2 a1 = *(const uint2*)(s0 + PN + j8);
    const uint2 a2 = *(const uint2*)(s0 + 2 * PN + j8);
    uint2 pk;
    pk.x = a0.x | (a1.x << 1) | (a2.x << 2);   // bytes are 0/1: no carry
    pk.y = a0.y | (a1.y << 1) | (a2.y << 2);
    ((uint2*)ssel32)[t] = pk;
  }
  __syncthreads();

  const int lane = t & 63;
  const int wv   = t >> 6;
  const int i    = (itile << 6) + lane;

  const float4 ri   = sroi[i];
  const float areai = (ri.z - ri.x) * (ri.w - ri.y);

  float bn0 = -2.0f, bn1 = -2.0f, bn2 = -2.0f;   // init matches masked = -2.0
  float bd0 =  1.0f, bd1 =  1.0f, bd2 =  1.0f;
  int   bj0 = 0,     bj1 = 0,     bj2 = 0;

  auto upd = [&](const float4 rj, const int jj, const u32 bits) {
    const float lx = fmaxf(ri.x, rj.x);
    const float ly = fmaxf(ri.y, rj.y);
    const float rx = fminf(ri.z, rj.z);
    const float ry = fminf(ri.w, rj.w);
    const float ww = fmaxf(rx - lx, 0.0f);
    const float hh = fmaxf(ry - ly, 0.0f);
    const float inter = ww * hh;
    const float areaj = (rj.z - rj.x) * (rj.w - rj.y);
    const float uni   = areai + areaj - inter;   // > 0 always (areas >= 1)
    // rational compare: inter/uni > bn/bd  <=>  inter*bd > bn*uni
    if (bits & 1u) { if (inter * bd0 > bn0 * uni) { bn0 = inter; bd0 = uni; bj0 = jj; } }
    if (bits & 2u) { if (inter * bd1 > bn1 * uni) { bn1 = inter; bd1 = uni; bj1 = jj; } }
    if (bits & 4u) { if (inter * bd2 > bn2 * uni) { bn2 = inter; bd2 = uni; bj2 = jj; } }
  };

  const int q0 = wv << 7;                        // 128 packed words = 512 j
  for (int q = q0; q < q0 + 128; ++q) {
    const u32 sb4 = ssel32[q];                   // wave-uniform
    const int j = q << 2;
    const float4 r0 = sroi[j + 0];               // broadcast reads, issued
    const float4 r1 = sroi[j + 1];               // before the skip-branch so
    const float4 r2 = sroi[j + 2];               // latency pipelines
    const float4 r3 = sroi[j + 3];
    if (sb4) {
      upd(r0, j + 0, sb4);
      upd(r1, j + 1, sb4 >> 8);
      upd(r2, j + 2, sb4 >> 16);
      upd(r3, j + 3, sb4 >> 24);
    }
  }

  rnLDS[wv][lane][0] = bn0; rnLDS[wv][lane][1] = bn1; rnLDS[wv][lane][2] = bn2;
  rdLDS[wv][lane][0] = bd0; rdLDS[wv][lane][1] = bd1; rdLDS[wv][lane][2] = bd2;
  rjLDS[wv][lane][0] = bj0; rjLDS[wv][lane][1] = bj1; rjLDS[wv][lane][2] = bj2;
  __syncthreads();

  if (wv == 0) {
    #pragma unroll
    for (int w2 = 1; w2 < 4; ++w2) {  // ascending chunk: strict > keeps first
      { const float n = rnLDS[w2][lane][0], d = rdLDS[w2][lane][0]; const int jj = rjLDS[w2][lane][0];
        if (n * bd0 > bn0 * d) { bn0 = n; bd0 = d; bj0 = jj; } }
      { const float n = rnLDS[w2][lane][1], d = rdLDS[w2][lane][1]; const int jj = rjLDS[w2][lane][1];
        if (n * bd1 > bn1 * d) { bn1 = n; bd1 = d; bj1 = jj; } }
      { const float n = rnLDS[w2][lane][2], d = rdLDS[w2][lane][2]; const int jj = rjLDS[w2][lane][2];
        if (n * bd2 > bn2 * d) { bn2 = n; bd2 = d; bj2 = jj; } }
    }
    const float v0 = bn0 / bd0;       // exact IEEE divide, once per (i,c)
    const float v1 = bn1 / bd1;
    const float v2 = bn2 / bd2;
    const float c0 = ps[(b * PN + bj0) * 4 + 0];
    const float c1 = ps[(b * PN + bj1) * 4 + 1];
    const float c2 = ps[(b * PN + bj2) * 4 + 2];
    float runI = -1.0f, runw = 1.0f;
    if (v0 > runI) { runw = c0; runI = v0; }
    if (v1 > runI) { runw = c1; runI = v1; }
    if (v2 > runI) { runw = c2; runI = v2; }
    const float y0 = (v0 > 0.5f) ? 1.0f : 0.0f;
    const float y1 = (v1 > 0.5f) ? 1.0f : 0.0f;
    const float y2 = (v2 > 0.5f) ? 1.0f : 0.0f;
    const float y3 = (y0 + y1 + y2 == 0.0f) ? 1.0f : 0.0f;

    const float4 lg = ((const float4*)logit)[b * PN + i];
    const float lb0 = labels[b * 4 + 0];
    const float lb1 = labels[b * 4 + 1];
    const float lb2 = labels[b * 4 + 2];

    auto term = [&](const float l, const float yv, const float labv) -> float {
      const float p  = fminf(fmaxf(l, 1e-7f), 1.0f - 1e-7f);
      const float om = 1.0f - p;
      const float fl = -yv * logf(p) * om * om;           // focal, gamma=2
      const float wl = 10.0f * expf(l) * (1.0f - labv) + labv;
      return runw * fl * wl;                              // /imb deferred
    };
    float s0 = term(lg.x, y0, lb0);
    float s1 = term(lg.y, y1, lb1);
    float s2 = term(lg.z, y2, lb2);
    float s3 = term(lg.w, y3, 1.0f);
    float z0 = y0, z1 = y1, z2 = y2, z3 = y3;
    #pragma unroll
    for (int off = 32; off; off >>= 1) {
      s0 += __shfl_xor(s0, off); s1 += __shfl_xor(s1, off);
      s2 += __shfl_xor(s2, off); s3 += __shfl_xor(s3, off);
      z0 += __shfl_xor(z0, off); z1 += __shfl_xor(z1, off);
      z2 += __shfl_xor(z2, off); z3 += __shfl_xor(z3, off);
    }
    if (lane == 0) {
      atomicAdd(&accum[0], s0); atomicAdd(&accum[1], s1);
      atomicAdd(&accum[2], s2); atomicAdd(&accum[3], s3);
      atomicAdd(&accum[4], z0); atomicAdd(&accum[5], z1);
      atomicAdd(&accum[6], z2); atomicAdd(&accum[7], z3);
    }
  }
}

// ---------------- K4: finalize loss ------------------------------------------
__global__ void k_final(const float* __restrict__ accum, float* __restrict__ loss)
{
  if (threadIdx.x == 0) {
    float L = 0.0f;
    #pragma unroll
    for (int c = 0; c < 4; ++c) L += accum[c] / (accum[4 + c] + 1e-7f);
    loss[0] = L * 0.125f;   // / bs, exact (power of two)
  }
}

extern "C" void kernel_launch(void* const* d_in, const int* in_sizes, int n_in,
                              void* d_out, int out_size, void* d_ws, size_t ws_size,
                              hipStream_t stream)
{
  (void)in_sizes; (void)n_in; (void)out_size; (void)ws_size;
  const float* inp    = (const float*)d_in[0];
  const float* fcw    = (const float*)d_in[1];
  const float* fcb    = (const float*)d_in[2];
  const float* ps     = (const float*)d_in[3];
  const float* labels = (const float*)d_in[4];
  const float* rois   = (const float*)d_in[5];
  float* out = (float*)d_out;                       // 65536 logit + 1 loss

  unsigned char* sel = (unsigned char*)d_ws;        // 3*8*2048 = 49152 B
  float* accum = (float*)((char*)d_ws + 49152);     // 8 floats (S[4], imb[4])

  hipMemsetAsync(accum, 0, 8 * sizeof(float), stream);
  k_fc_softmax<<<1024, 256, 0, stream>>>(inp, fcw, fcb, out);
  k_select   <<<24,   256, 0, stream>>>(ps, labels, sel);
  k_assign   <<<256,  256, 0, stream>>>(rois, ps, labels, sel, out, accum);
  k_final    <<<1,     64, 0, stream>>>(accum, out + BSZ * PN * 4);
}

// Round 2
// 139.641 us; speedup vs baseline: 1.2775x; 1.2775x over previous
//
#include <hip/hip_runtime.h>

typedef unsigned int u32;

#define BSZ 8
#define PN  2048
#define CIN 512
#define CAP 2056        // per-(b,c) list capacity (>=2048, mult of 8)
#define NW  16          // waves per k_assign block

// ws layout (bytes):
//   accum   @ 0       : 8 floats  (S[4], imb[4])
//   meta    @ 32      : 24 ints   (padded list length per (b,c))
//   sList   @ 1024    : 24*CAP floats  (score of selected j, list order)
//   roiList @ 198400  : 24*CAP float4  (roi of selected j, list order)
// total ~988 KB

// ---------------- K1: xr = inputs @ fc_w + fc_b ; logit = softmax(xr) --------
__global__ __launch_bounds__(256) void k_fc_softmax(
    const float* __restrict__ inp, const float* __restrict__ fcw,
    const float* __restrict__ fcb, float* __restrict__ logit)
{
  const int gw   = (blockIdx.x * blockDim.x + threadIdx.x) >> 6; // 0..4095
  const int lane = threadIdx.x & 63;
  const int kb   = lane << 2;

  const float4 wa0 = *(const float4*)(fcw + (kb + 0) * 4);
  const float4 wa1 = *(const float4*)(fcw + (kb + 1) * 4);
  const float4 wa2 = *(const float4*)(fcw + (kb + 2) * 4);
  const float4 wa3 = *(const float4*)(fcw + (kb + 3) * 4);
  const float4 wb0 = *(const float4*)(fcw + (256 + kb + 0) * 4);
  const float4 wb1 = *(const float4*)(fcw + (256 + kb + 1) * 4);
  const float4 wb2 = *(const float4*)(fcw + (256 + kb + 2) * 4);
  const float4 wb3 = *(const float4*)(fcw + (256 + kb + 3) * 4);
  const float4 bias = *(const float4*)fcb;

  #pragma unroll
  for (int rr = 0; rr < 4; ++rr) {
    const int r = (gw << 2) + rr;                 // row 0..16383
    const float* row = inp + r * CIN;
    const float4 xa = *(const float4*)(row + kb);
    const float4 xb = *(const float4*)(row + 256 + kb);
    float a0 = xa.x*wa0.x + xa.y*wa1.x + xa.z*wa2.x + xa.w*wa3.x
             + xb.x*wb0.x + xb.y*wb1.x + xb.z*wb2.x + xb.w*wb3.x;
    float a1 = xa.x*wa0.y + xa.y*wa1.y + xa.z*wa2.y + xa.w*wa3.y
             + xb.x*wb0.y + xb.y*wb1.y + xb.z*wb2.y + xb.w*wb3.y;
    float a2 = xa.x*wa0.z + xa.y*wa1.z + xa.z*wa2.z + xa.w*wa3.z
             + xb.x*wb0.z + xb.y*wb1.z + xb.z*wb2.z + xb.w*wb3.z;
    float a3 = xa.x*wa0.w + xa.y*wa1.w + xa.z*wa2.w + xa.w*wa3.w
             + xb.x*wb0.w + xb.y*wb1.w + xb.z*wb2.w + xb.w*wb3.w;
    #pragma unroll
    for (int off = 32; off; off >>= 1) {
      a0 += __shfl_xor(a0, off);
      a1 += __shfl_xor(a1, off);
      a2 += __shfl_xor(a2, off);
      a3 += __shfl_xor(a3, off);
    }
    if (lane == 0) {
      a0 += bias.x; a1 += bias.y; a2 += bias.z; a3 += bias.w;
      const float m  = fmaxf(fmaxf(a0, a1), fmaxf(a2, a3));
      const float e0 = expf(a0 - m), e1 = expf(a1 - m);
      const float e2 = expf(a2 - m), e3 = expf(a3 - m);
      const float inv = 1.0f / (e0 + e1 + e2 + e3);
      float4 o; o.x = e0 * inv; o.y = e1 * inv; o.z = e2 * inv; o.w = e3 * inv;
      *(float4*)(logit + r * 4) = o;
    }
  }
}

// ---------------- K2: selection -> compacted per-(b,c) roi/score lists ------
// sel_j = (labels[b,c]!=0) && (cnt>1 ? s_j>0.5 : j==argmax(s))
// Writes roiList/sList in ascending-j order, padded to multiple of 8 by
// repeating the last element (idempotent for the rational max).
__global__ __launch_bounds__(256) void k_select(
    const float* __restrict__ ps, const float* __restrict__ labels,
    const float* __restrict__ rois,
    int* __restrict__ meta, float* __restrict__ sList,
    float4* __restrict__ roiList)
{
  const int b = blockIdx.x / 3;
  const int c = blockIdx.x % 3;
  const int t = threadIdx.x;
  const int j0 = t * 8;                 // contiguous 8 per thread (list order)

  float sv[8];
  int   flg = 0, cnt = 0;
  float vmax = -1e30f;
  int   jmax = 0;
  #pragma unroll
  for (int m = 0; m < 8; ++m) {
    const float s = ps[(b * PN + j0 + m) * 4 + c];
    sv[m] = s;
    if (s > 0.5f) { flg |= 1 << m; ++cnt; }
    if (s > vmax) { vmax = s; jmax = j0 + m; }  // ascending: strict > = first
  }

  __shared__ float lv[256];
  __shared__ int   lj[256];
  __shared__ int   pre[256];
  lv[t] = vmax; lj[t] = jmax; pre[t] = cnt;
  __syncthreads();
  for (int off = 128; off > 0; off >>= 1) {     // argmax reduce
    if (t < off) {
      const float v2 = lv[t + off]; const int j2 = lj[t + off];
      if (v2 > lv[t] || (v2 == lv[t] && j2 < lj[t])) { lv[t] = v2; lj[t] = j2; }
    }
    __syncthreads();
  }
  for (int off = 1; off < 256; off <<= 1) {     // inclusive scan
    const int add = (t >= off) ? pre[t - off] : 0;
    __syncthreads();
    pre[t] += add;
    __syncthreads();
  }
  const int  totalTh = pre[255];
  const int  excl    = pre[t] - cnt;
  const int  jArg    = lj[0];
  const bool lab     = labels[b * 4 + c] != 0.0f;

  const int L    = (!lab) ? 0 : ((totalTh > 1) ? totalTh : 1);
  const int Lpad = (L + 7) & ~7;

  __shared__ float4 lastRoi;
  __shared__ float  lastS;
  float4* dstR = roiList + (b * 3 + c) * CAP;
  float*  dstS = sList   + (b * 3 + c) * CAP;
  const float4* rb = ((const float4*)rois) + b * PN;

  if (lab) {
    if (totalTh > 1) {
      int pos = excl;
      #pragma unroll
      for (int m = 0; m < 8; ++m) {
        if (flg & (1 << m)) {
          const float4 r = rb[j0 + m];
          dstR[pos] = r; dstS[pos] = sv[m];
          if (pos == L - 1) { lastRoi = r; lastS = sv[m]; }
          ++pos;
        }
      }
    } else if (t == (jArg >> 3)) {              // onehot: single element
      const float4 r = rb[jArg];
      dstR[0] = r; dstS[0] = sv[jArg & 7];
      lastRoi = r; lastS = sv[jArg & 7];
    }
  }
  __syncthreads();
  if (t < Lpad - L) { dstR[L + t] = lastRoi; dstS[L + t] = lastS; }
  if (t == 0) meta[b * 3 + c] = Lpad;
}

// ---------------- K3: IoU rational-argmax + loss partials --------------------
// block = (b, 64-i tile), 16 waves; lanes = i. Each wave takes a contiguous
// (ascending) chunk of each class list; 16-way LDS merge; epilogue on wave 0.
// Rational tracking (inter, union): divide once at the end — monotone, so the
// max VALUE is bit-identical to the reference.
__global__ __launch_bounds__(1024) void k_assign(
    const float* __restrict__ rois, const float* __restrict__ labels,
    const int* __restrict__ meta, const float* __restrict__ sList,
    const float4* __restrict__ roiList, const float* __restrict__ logit,
    float* __restrict__ accum)
{
  const int b     = blockIdx.x >> 5;
  const int itile = blockIdx.x & 31;
  const int t     = threadIdx.x;
  const int lane  = t & 63;
  const int wv    = t >> 6;
  const int i     = (itile << 6) + lane;

  const float4 ri   = ((const float4*)rois)[b * PN + i];
  const float areai = (ri.z - ri.x) * (ri.w - ri.y);

  __shared__ float mn[3][NW][64];
  __shared__ float md[3][NW][64];
  __shared__ int   mp[3][NW][64];

  float BN[3], BD[3];
  int   BP[3];

  #pragma unroll
  for (int c = 0; c < 3; ++c) {
    float bn = -2.0f, bd = 1.0f;   // matches masked = -2.0 init
    int   bp = 0;
    const int L = meta[b * 3 + c];
    const float4* base = roiList + (b * 3 + c) * CAP;
    const int C  = (((L + 15) >> 4) + 7) & ~7;  // per-wave chunk, mult of 8
    const int g0 = wv * C;
    int g1 = g0 + C; if (g1 > L) g1 = L;        // both mult of 8 -> full groups
    for (int g = g0; g < g1; g += 8) {
      float4 r[8];
      #pragma unroll
      for (int u = 0; u < 8; ++u) r[u] = base[g + u];   // broadcast loads
      #pragma unroll
      for (int u = 0; u < 8; ++u) {
        const float4 rj = r[u];
        const float lx = fmaxf(ri.x, rj.x);
        const float ly = fmaxf(ri.y, rj.y);
        const float rx = fminf(ri.z, rj.z);
        const float ry = fminf(ri.w, rj.w);
        const float ww = fmaxf(rx - lx, 0.0f);
        const float hh = fmaxf(ry - ly, 0.0f);
        const float inter = ww * hh;
        const float areaj = (rj.z - rj.x) * (rj.w - rj.y);
        const float uni   = areai + areaj - inter;      // >= 1 always
        if (inter * bd > bn * uni) { bn = inter; bd = uni; bp = g + u; }
      }
    }
    mn[c][wv][lane] = bn; md[c][wv][lane] = bd; mp[c][wv][lane] = bp;
    BN[c] = bn; BD[c] = bd; BP[c] = bp;
  }
  __syncthreads();

  if (wv == 0) {
    #pragma unroll
    for (int c = 0; c < 3; ++c) {
      float bn = BN[c], bd = BD[c]; int bp = BP[c];
      for (int w2 = 1; w2 < NW; ++w2) {   // ascending chunks: strict > = first
        const float n = mn[c][w2][lane], d = md[c][w2][lane];
        const int   p = mp[c][w2][lane];
        if (n * bd > bn * d) { bn = n; bd = d; bp = p; }
      }
      BN[c] = bn; BD[c] = bd; BP[c] = bp;
    }
    const float v0 = BN[0] / BD[0];       // exact IEEE divide, once per (i,c)
    const float v1 = BN[1] / BD[1];
    const float v2 = BN[2] / BD[2];
    const float c0 = sList[(b * 3 + 0) * CAP + BP[0]];
    const float c1 = sList[(b * 3 + 1) * CAP + BP[1]];
    const float c2 = sList[(b * 3 + 2) * CAP + BP[2]];
    float runI = -1.0f, runw = 1.0f;
    if (v0 > runI) { runw = c0; runI = v0; }
    if (v1 > runI) { runw = c1; runI = v1; }
    if (v2 > runI) { runw = c2; runI = v2; }
    const float y0 = (v0 > 0.5f) ? 1.0f : 0.0f;
    const float y1 = (v1 > 0.5f) ? 1.0f : 0.0f;
    const float y2 = (v2 > 0.5f) ? 1.0f : 0.0f;
    const float y3 = (y0 + y1 + y2 == 0.0f) ? 1.0f : 0.0f;

    const float4 lg = ((const float4*)logit)[b * PN + i];
    const float lb0 = labels[b * 4 + 0];
    const float lb1 = labels[b * 4 + 1];
    const float lb2 = labels[b * 4 + 2];

    auto term = [&](const float l, const float yv, const float labv) -> float {
      const float p  = fminf(fmaxf(l, 1e-7f), 1.0f - 1e-7f);
      const float om = 1.0f - p;
      const float fl = -yv * logf(p) * om * om;           // focal, gamma=2
      const float wl = 10.0f * expf(l) * (1.0f - labv) + labv;
      return runw * fl * wl;                              // /imb deferred
    };
    float s0 = term(lg.x, y0, lb0);
    float s1 = term(lg.y, y1, lb1);
    float s2 = term(lg.z, y2, lb2);
    float s3 = term(lg.w, y3, 1.0f);
    float z0 = y0, z1 = y1, z2 = y2, z3 = y3;
    #pragma unroll
    for (int off = 32; off; off >>= 1) {
      s0 += __shfl_xor(s0, off); s1 += __shfl_xor(s1, off);
      s2 += __shfl_xor(s2, off); s3 += __shfl_xor(s3, off);
      z0 += __shfl_xor(z0, off); z1 += __shfl_xor(z1, off);
      z2 += __shfl_xor(z2, off); z3 += __shfl_xor(z3, off);
    }
    if (lane == 0) {
      atomicAdd(&accum[0], s0); atomicAdd(&accum[1], s1);
      atomicAdd(&accum[2], s2); atomicAdd(&accum[3], s3);
      atomicAdd(&accum[4], z0); atomicAdd(&accum[5], z1);
      atomicAdd(&accum[6], z2); atomicAdd(&accum[7], z3);
    }
  }
}

// ---------------- K4: finalize loss ------------------------------------------
__global__ void k_final(const float* __restrict__ accum, float* __restrict__ loss)
{
  if (threadIdx.x == 0) {
    float L = 0.0f;
    #pragma unroll
    for (int c = 0; c < 4; ++c) L += accum[c] / (accum[4 + c] + 1e-7f);
    loss[0] = L * 0.125f;   // / bs, exact (power of two)
  }
}

extern "C" void kernel_launch(void* const* d_in, const int* in_sizes, int n_in,
                              void* d_out, int out_size, void* d_ws, size_t ws_size,
                              hipStream_t stream)
{
  (void)in_sizes; (void)n_in; (void)out_size; (void)ws_size;
  const float* inp    = (const float*)d_in[0];
  const float* fcw    = (const float*)d_in[1];
  const float* fcb    = (const float*)d_in[2];
  const float* ps     = (const float*)d_in[3];
  const float* labels = (const float*)d_in[4];
  const float* rois   = (const float*)d_in[5];
  float* out = (float*)d_out;                       // 65536 logit + 1 loss

  float*  accum   = (float*)d_ws;
  int*    meta    = (int*)((char*)d_ws + 32);
  float*  sList   = (float*)((char*)d_ws + 1024);
  float4* roiList = (float4*)((char*)d_ws + 198400);

  hipMemsetAsync(accum, 0, 8 * sizeof(float), stream);
  k_fc_softmax<<<1024, 256, 0, stream>>>(inp, fcw, fcb, out);
  k_select   <<<24,   256, 0, stream>>>(ps, labels, rois, meta, sList, roiList);
  k_assign   <<<256, 1024, 0, stream>>>(rois, labels, meta, sList, roiList, out, accum);
  k_final    <<<1,     64, 0, stream>>>(accum, out + BSZ * PN * 4);
}

// Round 3
// 116.794 us; speedup vs baseline: 1.5274x; 1.1956x over previous
//
#include <hip/hip_runtime.h>

#define BSZ 8
#define PN  2048
#define CIN 512
#define CAP 2048
#define NW  16

// ws layout (bytes):
//   accum @ 0       : 8 floats (S[4], imb[4])
//   meta  @ 64      : 24 ints (padded list length per (b,c))
//   sList @ 1024    : 24*2048 floats   (score, list order)
//   areaL @ 197632  : 24*2048 floats   (precomputed area)
//   roiL  @ 394240  : 24*2048 float4   (roi, list order)
//   pbn   @ 1180672 : 24*2*2048 floats (partial best numerator)
//   pbd   @ 1573888 : 24*2*2048 floats (partial best denominator)
//   pbp   @ 1967104 : 24*2*2048 ints   (partial best list position)
// total ~2.3 MB

// ---------------- K1: fc+softmax (blocks 0..1023) | select (1024..1047) -----
__global__ __launch_bounds__(256) void k_front(
    const float* __restrict__ inp, const float* __restrict__ fcw,
    const float* __restrict__ fcb, const float* __restrict__ ps,
    const float* __restrict__ labels, const float* __restrict__ rois,
    float* __restrict__ logit, float* __restrict__ accum,
    int* __restrict__ meta, float* __restrict__ sList,
    float* __restrict__ areaL, float4* __restrict__ roiList)
{
  const int t = threadIdx.x;
  if (blockIdx.x < 1024) {
    // ---- fc + softmax: wave-per-row, shuffle reduce ----
    const int gw   = (blockIdx.x * 256 + t) >> 6;   // 0..4095
    const int lane = t & 63;
    const int kb   = lane << 2;
    const float4 wa0 = *(const float4*)(fcw + (kb + 0) * 4);
    const float4 wa1 = *(const float4*)(fcw + (kb + 1) * 4);
    const float4 wa2 = *(const float4*)(fcw + (kb + 2) * 4);
    const float4 wa3 = *(const float4*)(fcw + (kb + 3) * 4);
    const float4 wb0 = *(const float4*)(fcw + (256 + kb + 0) * 4);
    const float4 wb1 = *(const float4*)(fcw + (256 + kb + 1) * 4);
    const float4 wb2 = *(const float4*)(fcw + (256 + kb + 2) * 4);
    const float4 wb3 = *(const float4*)(fcw + (256 + kb + 3) * 4);
    const float4 bias = *(const float4*)fcb;
    #pragma unroll
    for (int rr = 0; rr < 4; ++rr) {
      const int r = (gw << 2) + rr;                 // row 0..16383
      const float* row = inp + r * CIN;
      const float4 xa = *(const float4*)(row + kb);
      const float4 xb = *(const float4*)(row + 256 + kb);
      float a0 = xa.x*wa0.x + xa.y*wa1.x + xa.z*wa2.x + xa.w*wa3.x
               + xb.x*wb0.x + xb.y*wb1.x + xb.z*wb2.x + xb.w*wb3.x;
      float a1 = xa.x*wa0.y + xa.y*wa1.y + xa.z*wa2.y + xa.w*wa3.y
               + xb.x*wb0.y + xb.y*wb1.y + xb.z*wb2.y + xb.w*wb3.y;
      float a2 = xa.x*wa0.z + xa.y*wa1.z + xa.z*wa2.z + xa.w*wa3.z
               + xb.x*wb0.z + xb.y*wb1.z + xb.z*wb2.z + xb.w*wb3.z;
      float a3 = xa.x*wa0.w + xa.y*wa1.w + xa.z*wa2.w + xa.w*wa3.w
               + xb.x*wb0.w + xb.y*wb1.w + xb.z*wb2.w + xb.w*wb3.w;
      #pragma unroll
      for (int off = 32; off; off >>= 1) {
        a0 += __shfl_xor(a0, off); a1 += __shfl_xor(a1, off);
        a2 += __shfl_xor(a2, off); a3 += __shfl_xor(a3, off);
      }
      if (lane == 0) {
        a0 += bias.x; a1 += bias.y; a2 += bias.z; a3 += bias.w;
        const float m  = fmaxf(fmaxf(a0, a1), fmaxf(a2, a3));
        const float e0 = expf(a0 - m), e1 = expf(a1 - m);
        const float e2 = expf(a2 - m), e3 = expf(a3 - m);
        const float inv = 1.0f / (e0 + e1 + e2 + e3);
        float4 o; o.x = e0*inv; o.y = e1*inv; o.z = e2*inv; o.w = e3*inv;
        *(float4*)(logit + r * 4) = o;
      }
    }
    return;
  }

  // ---- selection -> compacted per-(b,c) lists (roi, area, score) ----
  const int bc = blockIdx.x - 1024;                 // 0..23
  if (bc == 0 && t < 8) accum[t] = 0.0f;            // replaces hipMemsetAsync
  const int b = bc / 3;
  const int c = bc % 3;
  const int j0 = t * 8;

  float sv[8];
  int   flg = 0, cnt = 0;
  float vmax = -1e30f;
  int   jmax = 0;
  #pragma unroll
  for (int m = 0; m < 8; ++m) {
    const float s = ps[(b * PN + j0 + m) * 4 + c];
    sv[m] = s;
    if (s > 0.5f) { flg |= 1 << m; ++cnt; }
    if (s > vmax) { vmax = s; jmax = j0 + m; }      // ascending: > = first
  }

  __shared__ float lv[256];
  __shared__ int   lj[256];
  __shared__ int   pre[256];
  lv[t] = vmax; lj[t] = jmax; pre[t] = cnt;
  __syncthreads();
  for (int off = 128; off > 0; off >>= 1) {         // argmax reduce
    if (t < off) {
      const float v2 = lv[t + off]; const int j2 = lj[t + off];
      if (v2 > lv[t] || (v2 == lv[t] && j2 < lj[t])) { lv[t] = v2; lj[t] = j2; }
    }
    __syncthreads();
  }
  for (int off = 1; off < 256; off <<= 1) {         // inclusive scan
    const int add = (t >= off) ? pre[t - off] : 0;
    __syncthreads();
    pre[t] += add;
    __syncthreads();
  }
  const int  totalTh = pre[255];
  const int  excl    = pre[t] - cnt;
  const int  jArg    = lj[0];
  const bool lab     = labels[b * 4 + c] != 0.0f;
  const int  L    = (!lab) ? 0 : ((totalTh > 1) ? totalTh : 1);
  const int  Lpad = (L + 7) & ~7;

  __shared__ float4 lastRoi;
  __shared__ float  lastS, lastA;
  float4* dstR = roiList + bc * CAP;
  float*  dstS = sList   + bc * CAP;
  float*  dstA = areaL   + bc * CAP;
  const float4* rb = ((const float4*)rois) + b * PN;

  if (lab) {
    if (totalTh > 1) {
      int pos = excl;
      #pragma unroll
      for (int m = 0; m < 8; ++m) {
        if (flg & (1 << m)) {
          const float4 r = rb[j0 + m];
          const float  a = (r.z - r.x) * (r.w - r.y);
          dstR[pos] = r; dstS[pos] = sv[m]; dstA[pos] = a;
          if (pos == L - 1) { lastRoi = r; lastS = sv[m]; lastA = a; }
          ++pos;
        }
      }
    } else if (t == (jArg >> 3)) {
      const float4 r = rb[jArg];
      const float  a = (r.z - r.x) * (r.w - r.y);
      dstR[0] = r; dstS[0] = sv[jArg & 7]; dstA[0] = a;
      lastRoi = r; lastS = sv[jArg & 7]; lastA = a;
    }
  }
  __syncthreads();
  if (t < Lpad - L) { dstR[L + t] = lastRoi; dstS[L + t] = lastS; dstA[L + t] = lastA; }
  if (t == 0) meta[bc] = Lpad;
}

// ---------------- K2: IoU rational-argmax partials ---------------------------
// block = (b, itile64, half h); 16 waves chunk the half-list; lists staged to
// LDS; dual accumulator chains; 16-way LDS merge; partial -> ws.
__global__ __launch_bounds__(1024, 8) void k_assign(
    const float* __restrict__ rois, const int* __restrict__ meta,
    const float4* __restrict__ roiList, const float* __restrict__ areaL,
    float* __restrict__ pbn, float* __restrict__ pbd, int* __restrict__ pbp)
{
  const int blk   = blockIdx.x;
  const int h     = blk & 1;
  const int itile = (blk >> 1) & 31;
  const int b     = blk >> 6;
  const int t     = threadIdx.x;
  const int lane  = t & 63;
  const int wv    = t >> 6;

  __shared__ __align__(16) char ldsraw[61440];      // 60 KB
  float4* sroi  = (float4*)ldsraw;                  // [3][1024] 48 KB
  float*  sarea = (float*)(ldsraw + 49152);         // [3][1024] 12 KB
  float*  mn    = (float*)ldsraw;                   // merge aliases (post-barrier)
  float*  md    = (float*)(ldsraw + 12288);
  int*    mp    = (int*)(ldsraw + 24576);

  int startc[3], cntc[3];
  #pragma unroll
  for (int c = 0; c < 3; ++c) {
    const int L  = meta[b * 3 + c];                 // padded, mult of 8
    const int L2 = ((L >> 1) + 7) & ~7;             // h-split point
    const int s0 = h ? L2 : 0;
    const int e0 = h ? L  : L2;
    startc[c] = s0;
    cntc[c]   = e0 - s0;                            // <= 1024, mult of 8
    if (t < cntc[c]) {                              // one coalesced step
      sroi [c * 1024 + t] = roiList[(b * 3 + c) * CAP + s0 + t];
      sarea[c * 1024 + t] = areaL  [(b * 3 + c) * CAP + s0 + t];
    }
  }
  const int i = (itile << 6) + lane;
  const float4 ri = ((const float4*)rois)[b * PN + i];
  const float areai = (ri.z - ri.x) * (ri.w - ri.y);
  __syncthreads();

  float BN[3], BD[3]; int BP[3];
  #pragma unroll
  for (int c = 0; c < 3; ++c) {
    const int cnt = cntc[c];
    const int C   = (((cnt + 15) >> 4) + 7) & ~7;   // per-wave chunk, mult 8
    const int g0  = wv * C;
    int g1 = g0 + C; if (g1 > cnt) g1 = cnt;
    float nA = -2.0f, dA = 1.0f, nB = -2.0f, dB = 1.0f;
    int   pA = 0, pB = 0;
    const float4* rbase = sroi  + c * 1024;
    const float*  abase = sarea + c * 1024;

    auto upd = [&](float& n, float& d, int& p,
                   const float4 rj, const float aj, const int pos) {
      const float lx = fmaxf(ri.x, rj.x), ly = fmaxf(ri.y, rj.y);
      const float rx = fminf(ri.z, rj.z), ry = fminf(ri.w, rj.w);
      const float ww = fmaxf(rx - lx, 0.0f), hh = fmaxf(ry - ly, 0.0f);
      const float inter = ww * hh;
      const float uni   = areai + aj - inter;       // >= 1 always
      if (inter * d > n * uni) { n = inter; d = uni; p = pos; }
    };

    for (int g = g0; g < g1; g += 4) {
      const float4 r0 = rbase[g], r1 = rbase[g+1], r2 = rbase[g+2], r3 = rbase[g+3];
      const float  a0 = abase[g], a1 = abase[g+1], a2 = abase[g+2], a3 = abase[g+3];
      upd(nA, dA, pA, r0, a0, g);                   // chain A: g, g+1, ...
      upd(nB, dB, pB, r2, a2, g + 2);               // chain B: g+2, g+3, ...
      upd(nA, dA, pA, r1, a1, g + 1);
      upd(nB, dB, pB, r3, a3, g + 3);
    }
    // merge B into A with exact-tie -> lower position (ref = first max)
    const float tB = nB * dA, tA = nA * dB;
    if (tB > tA || (tB == tA && pB < pA)) { nA = nB; dA = dB; pA = pB; }
    BN[c] = nA; BD[c] = dA; BP[c] = pA + startc[c];
  }
  __syncthreads();                                  // stage reads done
  #pragma unroll
  for (int c = 0; c < 3; ++c) {
    mn[(c * NW + wv) * 64 + lane] = BN[c];
    md[(c * NW + wv) * 64 + lane] = BD[c];
    mp[(c * NW + wv) * 64 + lane] = BP[c];
  }
  __syncthreads();
  if (wv == 0) {
    #pragma unroll
    for (int c = 0; c < 3; ++c) {
      float bn = BN[c], bd = BD[c]; int bp = BP[c];
      for (int w2 = 1; w2 < NW; ++w2) {             // wv-ascending: > = first
        const float n = mn[(c * NW + w2) * 64 + lane];
        const float d = md[(c * NW + w2) * 64 + lane];
        const int   p = mp[(c * NW + w2) * 64 + lane];
        if (n * bd > bn * d) { bn = n; bd = d; bp = p; }
      }
      const int o = ((b * 3 + c) * 2 + h) * PN + i;
      pbn[o] = bn; pbd[o] = bd; pbp[o] = bp;
    }
  }
}

// ---------------- K3: merge halves + epilogue + loss partials ----------------
__global__ __launch_bounds__(256) void k_back(
    const float* __restrict__ pbn, const float* __restrict__ pbd,
    const int* __restrict__ pbp, const float* __restrict__ sList,
    const float* __restrict__ logit, const float* __restrict__ labels,
    float* __restrict__ accum)
{
  const int t  = threadIdx.x;
  const int gi = blockIdx.x * 256 + t;              // 0..16383
  const int b  = gi >> 11;
  const int i  = gi & (PN - 1);

  float v[3], sc[3];
  #pragma unroll
  for (int c = 0; c < 3; ++c) {
    const int o0 = ((b * 3 + c) * 2) * PN + i;
    float n = pbn[o0], d = pbd[o0]; int p = pbp[o0];
    const float n1 = pbn[o0 + PN], d1 = pbd[o0 + PN];
    const int   p1 = pbp[o0 + PN];
    if (n1 * d > n * d1) { n = n1; d = d1; p = p1; }  // h-ascending: > = first
    v[c]  = n / d;                                    // exact IEEE divide
    sc[c] = sList[(b * 3 + c) * CAP + p];
  }
  float runI = -1.0f, runw = 1.0f;
  if (v[0] > runI) { runw = sc[0]; runI = v[0]; }
  if (v[1] > runI) { runw = sc[1]; runI = v[1]; }
  if (v[2] > runI) { runw = sc[2]; runI = v[2]; }
  const float y0 = (v[0] > 0.5f) ? 1.0f : 0.0f;
  const float y1 = (v[1] > 0.5f) ? 1.0f : 0.0f;
  const float y2 = (v[2] > 0.5f) ? 1.0f : 0.0f;
  const float y3 = (y0 + y1 + y2 == 0.0f) ? 1.0f : 0.0f;

  const float4 lg = ((const float4*)logit)[gi];
  const float lb0 = labels[b * 4 + 0];
  const float lb1 = labels[b * 4 + 1];
  const float lb2 = labels[b * 4 + 2];

  auto term = [&](const float l, const float yv, const float labv) -> float {
    const float p  = fminf(fmaxf(l, 1e-7f), 1.0f - 1e-7f);
    const float om = 1.0f - p;
    const float fl = -yv * logf(p) * om * om;       // focal, gamma=2
    const float wl = 10.0f * expf(l) * (1.0f - labv) + labv;
    return runw * fl * wl;                          // /imb deferred
  };
  float s[8];
  s[0] = term(lg.x, y0, lb0); s[1] = term(lg.y, y1, lb1);
  s[2] = term(lg.z, y2, lb2); s[3] = term(lg.w, y3, 1.0f);
  s[4] = y0; s[5] = y1; s[6] = y2; s[7] = y3;

  #pragma unroll
  for (int k = 0; k < 8; ++k)
    #pragma unroll
    for (int off = 32; off; off >>= 1) s[k] += __shfl_xor(s[k], off);

  __shared__ float red[4][8];
  const int wv = t >> 6;
  if ((t & 63) == 0)
    #pragma unroll
    for (int k = 0; k < 8; ++k) red[wv][k] = s[k];
  __syncthreads();
  if (t < 8) {
    const float sum = red[0][t] + red[1][t] + red[2][t] + red[3][t];
    atomicAdd(&accum[t], sum);
  }
}

// ---------------- K4: finalize loss ------------------------------------------
__global__ void k_final(const float* __restrict__ accum, float* __restrict__ loss)
{
  if (threadIdx.x == 0) {
    float L = 0.0f;
    #pragma unroll
    for (int c = 0; c < 4; ++c) L += accum[c] / (accum[4 + c] + 1e-7f);
    loss[0] = L * 0.125f;   // / bs, exact (power of two)
  }
}

extern "C" void kernel_launch(void* const* d_in, const int* in_sizes, int n_in,
                              void* d_out, int out_size, void* d_ws, size_t ws_size,
                              hipStream_t stream)
{
  (void)in_sizes; (void)n_in; (void)out_size; (void)ws_size;
  const float* inp    = (const float*)d_in[0];
  const float* fcw    = (const float*)d_in[1];
  const float* fcb    = (const float*)d_in[2];
  const float* ps     = (const float*)d_in[3];
  const float* labels = (const float*)d_in[4];
  const float* rois   = (const float*)d_in[5];
  float* out = (float*)d_out;                       // 65536 logit + 1 loss

  char* ws = (char*)d_ws;
  float*  accum   = (float*) (ws);
  int*    meta    = (int*)   (ws + 64);
  float*  sList   = (float*) (ws + 1024);
  float*  areaL   = (float*) (ws + 197632);
  float4* roiL    = (float4*)(ws + 394240);
  float*  pbn     = (float*) (ws + 1180672);
  float*  pbd     = (float*) (ws + 1573888);
  int*    pbp     = (int*)   (ws + 1967104);

  k_front <<<1048, 256, 0, stream>>>(inp, fcw, fcb, ps, labels, rois,
                                     out, accum, meta, sList, areaL, roiL);
  k_assign<<<512, 1024, 0, stream>>>(rois, meta, roiL, areaL, pbn, pbd, pbp);
  k_back  <<<64,   256, 0, stream>>>(pbn, pbd, pbp, sList, out, labels, accum);
  k_final <<<1,     64, 0, stream>>>(accum, out + BSZ * PN * 4);
}